// Round 1
// baseline (20.122 us; speedup 1.0000x reference)
//
#include <hip/hip_runtime.h>

// MoE: E=8 experts, each Linear(1->32) + ReLU + Linear(32->1).
// weights = softmax(-sum_p (pred_e(ctx_x_p) - ctx_y_p)^2) over experts,
// out[b]  = sum_e weights[b,e] * pred_e(input[b]).
//
// VALU-bound: ~3.9k fp32 ops/element. One thread per element, params read
// via wave-uniform addresses (scalarized to s_load), online softmax so no
// runtime-indexed arrays (avoid scratch).

constexpr int E = 8;
constexpr int H = 32;

__global__ __launch_bounds__(256) void moe_kernel(
    const float* __restrict__ ctx,   // [B, 8]
    const float* __restrict__ inp,   // [B, 1]
    const float* __restrict__ W1,    // [E, 1, H]
    const float* __restrict__ b1,    // [E, H]
    const float* __restrict__ W2,    // [E, H, 1]
    const float* __restrict__ b2,    // [E, 1]
    float* __restrict__ out,         // [B, 1]
    int B)
{
    const int b = blockIdx.x * blockDim.x + threadIdx.x;
    if (b >= B) return;

    // Coalesced 32B context read per lane.
    const float4 c0 = reinterpret_cast<const float4*>(ctx)[b * 2 + 0];
    const float4 c1 = reinterpret_cast<const float4*>(ctx)[b * 2 + 1];
    const float x0 = c0.x, y0 = c0.y;
    const float x1 = c0.z, y1 = c0.w;
    const float x2 = c1.x, y2 = c1.y;
    const float x3 = c1.z, y3 = c1.w;
    const float x4 = inp[b];

    // Online softmax(-err) accumulation: m = running min(err),
    // s = sum of exp(m - err_e), wo = sum of exp(m - err_e) * o_e.
    float m  = 3.0e38f;
    float s  = 0.0f;
    float wo = 0.0f;

    #pragma unroll 1   // keep e rolled: no cross-expert reuse, smaller code
    for (int e = 0; e < E; ++e) {
        const float* __restrict__ w1p = W1 + e * H;  // uniform -> s_load
        const float* __restrict__ b1p = b1 + e * H;
        const float* __restrict__ w2p = W2 + e * H;

        float a0 = 0.f, a1 = 0.f, a2 = 0.f, a3 = 0.f, a4 = 0.f;
        #pragma unroll
        for (int h = 0; h < H; ++h) {
            const float w1 = w1p[h];
            const float bb = b1p[h];
            const float w2 = w2p[h];
            a0 = fmaf(fmaxf(fmaf(x0, w1, bb), 0.f), w2, a0);
            a1 = fmaf(fmaxf(fmaf(x1, w1, bb), 0.f), w2, a1);
            a2 = fmaf(fmaxf(fmaf(x2, w1, bb), 0.f), w2, a2);
            a3 = fmaf(fmaxf(fmaf(x3, w1, bb), 0.f), w2, a3);
            a4 = fmaf(fmaxf(fmaf(x4, w1, bb), 0.f), w2, a4);
        }
        const float bias = b2[e];
        const float d0 = a0 + bias - y0;
        const float d1 = a1 + bias - y1;
        const float d2 = a2 + bias - y2;
        const float d3 = a3 + bias - y3;
        const float errv = fmaf(d0, d0, fmaf(d1, d1, fmaf(d2, d2, d3 * d3)));
        const float oe   = a4 + bias;

        const float nm   = fminf(m, errv);
        const float corr = __expf(nm - m);     // <=1; first iter: exp(-huge)=0
        const float w    = __expf(nm - errv);  // <=1
        s  = fmaf(s,  corr, w);
        wo = fmaf(wo, corr, w * oe);
        m  = nm;
    }

    out[b] = wo / s;
}

extern "C" void kernel_launch(void* const* d_in, const int* in_sizes, int n_in,
                              void* d_out, int out_size, void* d_ws, size_t ws_size,
                              hipStream_t stream) {
    const float* ctx = (const float*)d_in[0];
    const float* inp = (const float*)d_in[1];
    const float* W1  = (const float*)d_in[2];
    const float* b1  = (const float*)d_in[3];
    const float* W2  = (const float*)d_in[4];
    const float* b2  = (const float*)d_in[5];
    float* out = (float*)d_out;

    const int B = in_sizes[1];  // input is [B,1]
    const int threads = 256;
    const int blocks = (B + threads - 1) / threads;
    hipLaunchKernelGGL(moe_kernel, dim3(blocks), dim3(threads), 0, stream,
                       ctx, inp, W1, b1, W2, b2, out, B);
}

// Round 2
// 15.154 us; speedup vs baseline: 1.3278x; 1.3278x over previous
//
#include <hip/hip_runtime.h>

// MoE: E=8 experts, Linear(1->32)+ReLU+Linear(32->1), softmax(-sq_err over 4
// context points) weighting.
//
// Round-2 design:
//  - thread = (element b, expert e): 8x wave count vs round 1 (2 -> 16
//    waves/SIMD of work) to hide fma/LDS latency.
//  - algebraic rewrite: w2*relu(w1*x+b1) = 0.5*w2*w1*x + 0.5*w2*b1 + c*|x-r|,
//    c = 0.5*w2*|w1|, r = -b1/w1  ->  pred(x) = alpha*x + beta + sum_h c_h|x-r_h|
//    => 2 VALU ops per (h,eval) (v_sub + v_fma with free |.| modifier).
//  - per-block fused prologue computes (c,r,alpha,beta) into LDS (E*H = 256
//    threads, one per (e,h); shuffle-reduce alpha/beta over h).
//  - LDS layout [h][e] float2 -> ds_read_b64 hits 16 distinct banks per
//    8-lane group, broadcast across groups: conflict-free.
//  - softmax over e = 3x __shfl_xor (masks 1,2,4) within 8-lane groups.

constexpr int E = 8;
constexpr int H = 32;

__global__ __launch_bounds__(256) void moe_kernel(
    const float* __restrict__ ctx,   // [B, 8]
    const float* __restrict__ inp,   // [B, 1]
    const float* __restrict__ W1,    // [E, 1, H]
    const float* __restrict__ b1,    // [E, H]
    const float* __restrict__ W2,    // [E, H, 1]
    const float* __restrict__ b2,    // [E, 1]
    float* __restrict__ out,         // [B, 1]
    int B)
{
    // lds: [0..511] = (c,r) float2 pairs in [h][e] order; [512..519]=alpha[e];
    // [520..527]=beta[e]
    __shared__ __align__(16) float lds[528];

    // ---- fused prologue: all 256 threads, one per (e,h) ----
    {
        const int t = threadIdx.x;
        const int e = t >> 5;        // 0..7
        const int h = t & 31;        // 0..31
        const float w1  = W1[e * H + h];
        const float b1v = b1[e * H + h];
        const float w2  = W2[e * H + h];
        const float aw  = fabsf(w1);
        const bool tiny = aw < 1e-20f;
        const float c  = tiny ? 0.f : 0.5f * w2 * aw;
        const float r  = tiny ? 0.f : (-b1v / w1);
        float pa = tiny ? 0.f : 0.5f * w2 * w1;
        float pb = tiny ? (w2 * fmaxf(b1v, 0.f)) : (0.5f * w2 * b1v);

        reinterpret_cast<float2*>(lds)[h * E + e] = make_float2(c, r);

        // reduce pa,pb over the 32 h-lanes (masks <= 16 stay within e-half)
        #pragma unroll
        for (int m = 1; m < 32; m <<= 1) {
            pa += __shfl_xor(pa, m);
            pb += __shfl_xor(pb, m);
        }
        if (h == 0) {
            lds[512 + e] = pa;
            lds[520 + e] = pb + b2[e];
        }
    }
    __syncthreads();

    const int g = blockIdx.x * 256 + threadIdx.x;
    const int b = g >> 3;
    const int e = g & 7;
    if (b >= B) return;

    // context: 8 lanes of a group share b -> L1 broadcast
    const float4 c0 = reinterpret_cast<const float4*>(ctx)[b * 2 + 0];
    const float4 c1 = reinterpret_cast<const float4*>(ctx)[b * 2 + 1];
    const float x4 = inp[b];

    float a0 = 0.f, a1 = 0.f, a2 = 0.f, a3 = 0.f, a4 = 0.f;
    const float2* __restrict__ crs = reinterpret_cast<const float2*>(lds);
    #pragma unroll
    for (int h = 0; h < H; ++h) {
        const float2 cr = crs[h * E + e];   // ds_read_b64, conflict-free
        a0 = fmaf(cr.x, fabsf(c0.x - cr.y), a0);
        a1 = fmaf(cr.x, fabsf(c0.z - cr.y), a1);
        a2 = fmaf(cr.x, fabsf(c1.x - cr.y), a2);
        a3 = fmaf(cr.x, fabsf(c1.z - cr.y), a3);
        a4 = fmaf(cr.x, fabsf(x4  - cr.y), a4);
    }

    const float alpha = lds[512 + e];
    const float beta  = lds[520 + e];
    const float p0 = fmaf(alpha, c0.x, beta + a0) - c0.y;
    const float p1 = fmaf(alpha, c0.z, beta + a1) - c0.w;
    const float p2 = fmaf(alpha, c1.x, beta + a2) - c1.y;
    const float p3 = fmaf(alpha, c1.z, beta + a3) - c1.w;
    const float err = fmaf(p0, p0, fmaf(p1, p1, fmaf(p2, p2, p3 * p3)));
    const float oe  = fmaf(alpha, x4, beta + a4);

    // softmax(-err) over the 8 experts living in this 8-lane group
    float m = err;
    m = fminf(m, __shfl_xor(m, 1));
    m = fminf(m, __shfl_xor(m, 2));
    m = fminf(m, __shfl_xor(m, 4));
    const float w = __expf(m - err);
    float s  = w;
    float wo = w * oe;
    s  += __shfl_xor(s, 1);  wo += __shfl_xor(wo, 1);
    s  += __shfl_xor(s, 2);  wo += __shfl_xor(wo, 2);
    s  += __shfl_xor(s, 4);  wo += __shfl_xor(wo, 4);

    if (e == 0) out[b] = wo / s;
}

extern "C" void kernel_launch(void* const* d_in, const int* in_sizes, int n_in,
                              void* d_out, int out_size, void* d_ws, size_t ws_size,
                              hipStream_t stream) {
    const float* ctx = (const float*)d_in[0];
    const float* inp = (const float*)d_in[1];
    const float* W1  = (const float*)d_in[2];
    const float* b1  = (const float*)d_in[3];
    const float* W2  = (const float*)d_in[4];
    const float* b2  = (const float*)d_in[5];
    float* out = (float*)d_out;

    const int B = in_sizes[1];  // input is [B,1]
    const long long total = (long long)B * 8;
    const int threads = 256;
    const int blocks = (int)((total + threads - 1) / threads);
    hipLaunchKernelGGL(moe_kernel, dim3(blocks), dim3(threads), 0, stream,
                       ctx, inp, W1, b1, W2, b2, out, B);
}

// Round 3
// 15.149 us; speedup vs baseline: 1.3283x; 1.0004x over previous
//
#include <hip/hip_runtime.h>

// MoE: E=8 experts, Linear(1->32)+ReLU+Linear(32->1), softmax(-sq_err over 4
// context points) weighting.
//
// Round-3 design (vs round 2):
//  - pred_e(x) = sum_{i=0}^{32} c_i |x - r_i| + K  (alpha/beta folded in:
//    entry 32 = (alpha, -16) since all |x| < 16, K = beta - 16*alpha).
//  - each thread preloads its expert's FULL table into registers
//    (17x ds_read_b128, static indices) -> inner loop is pure VALU,
//    zero memory ops, no lgkmcnt stalls possible.
//  - table rows padded to 34 float2 (272 B): row base bank = 4e ->
//    the 8 lanes of a group hit disjoint bank quads; groups broadcast.
//  - thread = (b, e), softmax over e via 3x __shfl_xor in 8-lane groups.

constexpr int E = 8;
constexpr int H = 32;
constexpr int STRIDE = 34;  // float2 per expert row: 32 knots + alpha-entry + K, padded

__global__ __launch_bounds__(256) void moe_kernel(
    const float* __restrict__ ctx,   // [B, 8]
    const float* __restrict__ inp,   // [B, 1]
    const float* __restrict__ W1,    // [E, 1, H]
    const float* __restrict__ b1,    // [E, H]
    const float* __restrict__ W2,    // [E, H, 1]
    const float* __restrict__ b2,    // [E, 1]
    float* __restrict__ out,         // [B, 1]
    int B)
{
    __shared__ __align__(16) float2 crs[E * STRIDE];  // 2176 B

    const int t = threadIdx.x;
    {
        // prologue: one thread per (e,h). relu(z) = 0.5z + 0.5|z| =>
        // w2*relu(w1 x + b1) = (0.5 w2 w1) x + (0.5 w2 b1) + (0.5 w2|w1|)|x + b1/w1|
        const int e = t >> 5;        // 0..7
        const int h = t & 31;        // 0..31
        const float w1  = W1[e * H + h];
        const float b1v = b1[e * H + h];
        const float w2  = W2[e * H + h];
        const float aw  = fabsf(w1);
        const bool tiny = aw < 1e-20f;
        const float c = tiny ? 0.f : 0.5f * w2 * aw;
        const float r = tiny ? 0.f : (-b1v / w1);
        float pa = tiny ? 0.f : 0.5f * w2 * w1;
        float pb = tiny ? (w2 * fmaxf(b1v, 0.f)) : (0.5f * w2 * b1v);

        crs[e * STRIDE + h] = make_float2(c, r);

        #pragma unroll
        for (int m = 1; m < 32; m <<= 1) {   // reduce over the 32 h-lanes
            pa += __shfl_xor(pa, m);
            pb += __shfl_xor(pb, m);
        }
        if (h == 0) {
            const float beta = pb + b2[e];
            crs[e * STRIDE + 32] = make_float2(pa, -16.0f);      // alpha*|x+16|
            crs[e * STRIDE + 33] = make_float2(beta - 16.0f * pa, 0.f);  // K
        }
    }
    __syncthreads();

    const int g = blockIdx.x * 256 + t;
    const int b = g >> 3;
    const int e = g & 7;
    if (b >= B) return;

    // context (8 lanes of a group share b -> dedup'd by L1)
    const float4 c0 = reinterpret_cast<const float4*>(ctx)[b * 2 + 0];
    const float4 c1 = reinterpret_cast<const float4*>(ctx)[b * 2 + 1];
    const float x4 = inp[b];

    // preload this expert's table into registers: 17x ds_read_b128,
    // conflict-free (row base byte e*272 -> bank 4e, disjoint per lane-group)
    float4 crq[17];
    const float4* __restrict__ rowp =
        reinterpret_cast<const float4*>(&crs[e * STRIDE]);
    #pragma unroll
    for (int i = 0; i < 17; ++i) crq[i] = rowp[i];

    const float K = crq[16].z;
    float a0 = K, a1 = K, a2 = K, a3 = K, a4 = K;

    #pragma unroll
    for (int i = 0; i < 16; ++i) {
        {
            const float c = crq[i].x, r = crq[i].y;
            a0 = fmaf(c, fabsf(c0.x - r), a0);
            a1 = fmaf(c, fabsf(c0.z - r), a1);
            a2 = fmaf(c, fabsf(c1.x - r), a2);
            a3 = fmaf(c, fabsf(c1.z - r), a3);
            a4 = fmaf(c, fabsf(x4  - r), a4);
        }
        {
            const float c = crq[i].z, r = crq[i].w;
            a0 = fmaf(c, fabsf(c0.x - r), a0);
            a1 = fmaf(c, fabsf(c0.z - r), a1);
            a2 = fmaf(c, fabsf(c1.x - r), a2);
            a3 = fmaf(c, fabsf(c1.z - r), a3);
            a4 = fmaf(c, fabsf(x4  - r), a4);
        }
    }
    {   // entry 32: alpha * |x + 16|
        const float c = crq[16].x, r = crq[16].y;
        a0 = fmaf(c, fabsf(c0.x - r), a0);
        a1 = fmaf(c, fabsf(c0.z - r), a1);
        a2 = fmaf(c, fabsf(c1.x - r), a2);
        a3 = fmaf(c, fabsf(c1.z - r), a3);
        a4 = fmaf(c, fabsf(x4  - r), a4);
    }

    const float p0 = a0 - c0.y;
    const float p1 = a1 - c0.w;
    const float p2 = a2 - c1.y;
    const float p3 = a3 - c1.w;
    const float err = fmaf(p0, p0, fmaf(p1, p1, fmaf(p2, p2, p3 * p3)));
    const float oe  = a4;

    // softmax(-err) over the 8 experts in this 8-lane group
    float m = err;
    m = fminf(m, __shfl_xor(m, 1));
    m = fminf(m, __shfl_xor(m, 2));
    m = fminf(m, __shfl_xor(m, 4));
    const float w = __expf(m - err);
    float s  = w;
    float wo = w * oe;
    s  += __shfl_xor(s, 1);  wo += __shfl_xor(wo, 1);
    s  += __shfl_xor(s, 2);  wo += __shfl_xor(wo, 2);
    s  += __shfl_xor(s, 4);  wo += __shfl_xor(wo, 4);

    if (e == 0) out[b] = wo / s;
}

extern "C" void kernel_launch(void* const* d_in, const int* in_sizes, int n_in,
                              void* d_out, int out_size, void* d_ws, size_t ws_size,
                              hipStream_t stream) {
    const float* ctx = (const float*)d_in[0];
    const float* inp = (const float*)d_in[1];
    const float* W1  = (const float*)d_in[2];
    const float* b1  = (const float*)d_in[3];
    const float* W2  = (const float*)d_in[4];
    const float* b2  = (const float*)d_in[5];
    float* out = (float*)d_out;

    const int B = in_sizes[1];  // input is [B,1]
    const long long total = (long long)B * 8;
    const int threads = 256;
    const int blocks = (int)((total + threads - 1) / threads);
    hipLaunchKernelGGL(moe_kernel, dim3(blocks), dim3(threads), 0, stream,
                       ctx, inp, W1, b1, W2, b2, out, B);
}